// Round 5
// baseline (210.210 us; speedup 1.0000x reference)
//
#include <hip/hip_runtime.h>
#include <math.h>

// MoE router: logits[16384,64] = X[16384,2048] @ W^T (fp32), top-2, softmax(2).
// Outputs flat: weights [16384*2] f32, then indices [16384*2] as float.
//
// R1: runtime-indexed acc -> scratch spill.
// R3: register-staged LDS tiles -> spill (2.7GB).
// R4: worked (176us) but FETCH=488MB vs 134 compulsory: experts split across
//     4 waves -> every X line fetched 4x. Memory-bound at 25% VALU.
// R5 design: one lane owns ONE token x ALL 64 experts.
//   - X read exactly once; each lane consumes full 64B lines (4 float4s).
//   - W is wave-uniform -> scalar loads (s_load_dwordx4) via constant cache;
//     no LDS anywhere, no barriers.
//   - acc[64] + xv ping-pong (32 regs), all statically indexed (~110 VGPR).
//   - split-D NS=8 (ws>=32MB proven in R4): 512 blocks x 256 thr, 2 blk/CU.
//   - reduce kernel: ascending-slice sum + top-2 + softmax (proven R4).

#define NTOK 16384
#define DDIM 2048
#define NEXP 64
#define D16 16
#define SLICE_ELTS (NTOK * NEXP)

template <int NS>
__global__ __launch_bounds__(256, 2) void moe_partial_kernel(
    const float* __restrict__ x,      // [NTOK, DDIM]
    const float* __restrict__ gw,     // [NEXP, DDIM]
    float* __restrict__ ws)           // [NS][NTOK][NEXP]
{
    const int DSL = DDIM / NS;        // d per slice
    const int NCH = DSL / D16;        // d16 chunks per slice

    const int tid   = threadIdx.x;
    const int dsl   = blockIdx.x & (NS - 1);
    const int tg    = blockIdx.x / NS;
    const int token = tg * 256 + tid;
    const int d0    = dsl * DSL;

    const float* xrow  = x  + (size_t)token * DDIM + d0;
    const float* wbase = gw + d0;

    float acc[NEXP];
#pragma unroll
    for (int e = 0; e < NEXP; ++e) acc[e] = 0.f;

    // xv ping-pong: lane consumes its full 64B line per chunk
    float4 xa[4], xb[4];
#pragma unroll
    for (int q = 0; q < 4; ++q)
        xa[q] = *reinterpret_cast<const float4*>(xrow + q * 4);

    for (int ch = 0; ch < NCH; ++ch) {
        if (ch + 1 < NCH) {           // uniform condition: no divergence
#pragma unroll
            for (int q = 0; q < 4; ++q)
                xb[q] = *reinterpret_cast<const float4*>(
                    xrow + (ch + 1) * D16 + q * 4);
        }

        const float* wc = wbase + ch * D16;
#pragma unroll
        for (int e = 0; e < NEXP; ++e) {
            // wave-uniform address -> scalar loads through constant cache
            const float4* wr =
                reinterpret_cast<const float4*>(wc + (size_t)e * DDIM);
            float s = acc[e];
#pragma unroll
            for (int q = 0; q < 4; ++q) {
                float4 wv = wr[q];
                s = fmaf(xa[q].x, wv.x, s);
                s = fmaf(xa[q].y, wv.y, s);
                s = fmaf(xa[q].z, wv.z, s);
                s = fmaf(xa[q].w, wv.w, s);
            }
            acc[e] = s;
        }

#pragma unroll
        for (int q = 0; q < 4; ++q) xa[q] = xb[q];
    }

    // partials: ws[dsl][token][e], 256B contiguous per lane -> coalesced
    float* row = ws + (size_t)dsl * SLICE_ELTS + (size_t)token * NEXP;
#pragma unroll
    for (int q = 0; q < 16; ++q) {
        float4 v = make_float4(acc[q * 4 + 0], acc[q * 4 + 1],
                               acc[q * 4 + 2], acc[q * 4 + 3]);
        *reinterpret_cast<float4*>(row + q * 4) = v;
    }
}

template <int NS>
__global__ __launch_bounds__(128) void moe_reduce_kernel(
    const float* __restrict__ ws,     // [NS][NTOK][NEXP]
    float* __restrict__ out)          // weights then indices
{
    const int t = blockIdx.x * 128 + threadIdx.x;   // token
    float m1 = -INFINITY, m2 = -INFINITY;
    int i1 = 0, i2 = 0;

    const float* base = ws + (size_t)t * NEXP;
    for (int e4 = 0; e4 < 16; ++e4) {
        float4 s = *reinterpret_cast<const float4*>(base + e4 * 4);
#pragma unroll
        for (int sl = 1; sl < NS; ++sl) {           // ascending-D order
            float4 p = *reinterpret_cast<const float4*>(
                base + (size_t)sl * SLICE_ELTS + e4 * 4);
            s.x += p.x; s.y += p.y; s.z += p.z; s.w += p.w;
        }
        float v[4] = {s.x, s.y, s.z, s.w};
#pragma unroll
        for (int q = 0; q < 4; ++q) {
            const int e = e4 * 4 + q;
            if (v[q] > m1) {            // strict '>' = lowest index on ties
                m2 = m1; i2 = i1;
                m1 = v[q]; i1 = e;
            } else if (v[q] > m2) {
                m2 = v[q]; i2 = e;
            }
        }
    }

    float e2 = expf(m2 - m1);
    float denom = 1.f + e2;
    out[t * 2 + 0] = 1.f / denom;
    out[t * 2 + 1] = e2 / denom;
    out[NTOK * 2 + t * 2 + 0] = (float)i1;
    out[NTOK * 2 + t * 2 + 1] = (float)i2;
}

template <int NS>
static void launch_ns(const float* x, const float* gw, float* ws, float* out,
                      hipStream_t stream) {
    moe_partial_kernel<NS>
        <<<dim3((NTOK / 256) * NS), dim3(256), 0, stream>>>(x, gw, ws);
    moe_reduce_kernel<NS>
        <<<dim3(NTOK / 128), dim3(128), 0, stream>>>(ws, out);
}

extern "C" void kernel_launch(void* const* d_in, const int* in_sizes, int n_in,
                              void* d_out, int out_size, void* d_ws, size_t ws_size,
                              hipStream_t stream) {
    const float* x  = (const float*)d_in[0];   // [4,4096,2048] f32
    const float* gw = (const float*)d_in[1];   // [64,2048] f32
    float* out = (float*)d_out;
    float* ws  = (float*)d_ws;

    const size_t per_slice = (size_t)SLICE_ELTS * sizeof(float);  // 4 MiB
    if      (ws_size >= 8 * per_slice) launch_ns<8>(x, gw, ws, out, stream);
    else if (ws_size >= 4 * per_slice) launch_ns<4>(x, gw, ws, out, stream);
    else if (ws_size >= 2 * per_slice) launch_ns<2>(x, gw, ws, out, stream);
    else                               launch_ns<1>(x, gw, ws, out, stream);
}

// Round 6
// 141.811 us; speedup vs baseline: 1.4823x; 1.4823x over previous
//
#include <hip/hip_runtime.h>
#include <math.h>

// MoE router: logits[16384,64] = X[16384,2048] @ W^T (fp32), top-2, softmax(2).
// Outputs flat: weights [16384*2] f32, then indices [16384*2] as float.
//
// R1: runtime-indexed acc -> scratch spill.
// R3: register-staged LDS tiles -> spill (2.7GB traffic).
// R4: W-in-LDS, 4 waves x 16 experts, 4 tok/lane: 167us but FETCH=488MB --
//     all 4 waves read the same X window; 64KB/chunk x 64 blocks/XCD > L2
//     -> duplication fell through to HBM.
// R5: W via wave-uniform scalar loads: FETCH=129MB (compulsory!) but 277us --
//     dependent s_load chains to L2, no prefetch depth. W needs LDS.
// R6 = R4 with two fixes:
//     (a) DC 64->32: per-block chunk window 32KB -> ~2MB/XCD concurrent
//         footprint -> L2 absorbs the intra-block 4-wave duplication.
//     (b) X ping-pong at d4 granularity: loads for d4+1 issue under d4's FMAs.

#define NTOK 16384
#define DDIM 2048
#define NEXP 64
#define DC 32                      // d per LDS chunk
#define SLICE_ELTS (NTOK * NEXP)   // floats per ws slice

__device__ static inline void gload_lds16(const float* gsrc, float* ldst) {
    __builtin_amdgcn_global_load_lds(
        (const __attribute__((address_space(1))) void*)gsrc,
        (__attribute__((address_space(3))) void*)ldst, 16, 0, 0);
}

template <int NS>
__global__ __launch_bounds__(256, 2) void moe_partial_kernel(
    const float* __restrict__ x,      // [NTOK, DDIM]
    const float* __restrict__ gw,     // [NEXP, DDIM]
    float* __restrict__ ws)           // [NS][NTOK][NEXP]
{
    __shared__ float Wl[2][NEXP * DC];   // 2 x 8 KB, [e][d] row-major

    const int tid  = threadIdx.x;
    const int lane = tid & 63;
    const int eg   = __builtin_amdgcn_readfirstlane(tid >> 6); // 0..3
    const int dsl  = blockIdx.x & (NS - 1);
    const int tg   = blockIdx.x / NS;
    const int T0   = tg * 256;
    const int DSL  = DDIM / NS;          // 256 for NS=8
    const int NCH  = DSL / DC;           // 8
    const int d0   = dsl * DSL;

    // W chunk = [64 e][32 d] = 8KB = 512 x 16B units; 2 units/thread.
    // unit u: e = u>>3, dq = u&7. LDS dest = wave-uniform base + lane*16 (ok).
#define STAGE(ch, buf)                                                        \
    {                                                                         \
        const int dcol = d0 + (ch) * DC;                                      \
        _Pragma("unroll")                                                     \
        for (int s = 0; s < 2; ++s) {                                         \
            const int u = tid + s * 256;                                      \
            gload_lds16(gw + (size_t)(u >> 3) * DDIM + dcol + (u & 7) * 4,    \
                        &Wl[buf][u * 4]);                                     \
        }                                                                     \
    }

    float acc[4][16];
#pragma unroll
    for (int t = 0; t < 4; ++t)
#pragma unroll
        for (int e = 0; e < 16; ++e) acc[t][e] = 0.f;

    const float* xbase = x + (size_t)(T0 + lane) * DDIM + d0;

    STAGE(0, 0);
    __syncthreads();

    int cur = 0;
    for (int ch = 0; ch < NCH; ++ch) {
        if (ch + 1 < NCH) STAGE(ch + 1, cur ^ 1);   // async DMA, no registers

        const float* Wc = &Wl[cur][eg * 16 * DC];   // this wave's 16 experts
        const float* xc = xbase + ch * DC;

        float4 xa[4], xb[4];
#pragma unroll
        for (int t = 0; t < 4; ++t)
            xa[t] = *reinterpret_cast<const float4*>(xc + (size_t)t * 64 * DDIM);

        for (int d4 = 0; d4 < DC / 4; ++d4) {       // dynamic: small body
            if (d4 + 1 < DC / 4) {                  // prefetch next d4 step
#pragma unroll
                for (int t = 0; t < 4; ++t)
                    xb[t] = *reinterpret_cast<const float4*>(
                        xc + (size_t)t * 64 * DDIM + (d4 + 1) * 4);
            }
#pragma unroll
            for (int e = 0; e < 16; ++e) {
                // wave-uniform LDS address -> broadcast, conflict-free
                float4 wv = *reinterpret_cast<const float4*>(
                    Wc + e * DC + d4 * 4);
#pragma unroll
                for (int t = 0; t < 4; ++t) {
                    acc[t][e] = fmaf(xa[t].x, wv.x, acc[t][e]);
                    acc[t][e] = fmaf(xa[t].y, wv.y, acc[t][e]);
                    acc[t][e] = fmaf(xa[t].z, wv.z, acc[t][e]);
                    acc[t][e] = fmaf(xa[t].w, wv.w, acc[t][e]);
                }
            }
#pragma unroll
            for (int t = 0; t < 4; ++t) xa[t] = xb[t];
        }
        __syncthreads();
        cur ^= 1;
    }
#undef STAGE

    // partials: ws[dsl][tok][exp], 64B contiguous per lane per token group
    float* wsl = ws + (size_t)dsl * SLICE_ELTS;
#pragma unroll
    for (int t = 0; t < 4; ++t) {
        float* row = wsl + (size_t)(T0 + lane + 64 * t) * NEXP + eg * 16;
#pragma unroll
        for (int q = 0; q < 4; ++q) {
            float4 v = make_float4(acc[t][q * 4 + 0], acc[t][q * 4 + 1],
                                   acc[t][q * 4 + 2], acc[t][q * 4 + 3]);
            *reinterpret_cast<float4*>(row + q * 4) = v;
        }
    }
}

template <int NS>
__global__ __launch_bounds__(128) void moe_reduce_kernel(
    const float* __restrict__ ws,     // [NS][NTOK][NEXP]
    float* __restrict__ out)          // weights then indices
{
    const int t = blockIdx.x * 128 + threadIdx.x;   // token
    float m1 = -INFINITY, m2 = -INFINITY;
    int i1 = 0, i2 = 0;

    const float* base = ws + (size_t)t * NEXP;
    for (int e4 = 0; e4 < 16; ++e4) {
        float4 s = *reinterpret_cast<const float4*>(base + e4 * 4);
#pragma unroll
        for (int sl = 1; sl < NS; ++sl) {           // ascending-D order
            float4 p = *reinterpret_cast<const float4*>(
                base + (size_t)sl * SLICE_ELTS + e4 * 4);
            s.x += p.x; s.y += p.y; s.z += p.z; s.w += p.w;
        }
        float v[4] = {s.x, s.y, s.z, s.w};
#pragma unroll
        for (int q = 0; q < 4; ++q) {
            const int e = e4 * 4 + q;
            if (v[q] > m1) {            // strict '>' = lowest index on ties
                m2 = m1; i2 = i1;
                m1 = v[q]; i1 = e;
            } else if (v[q] > m2) {
                m2 = v[q]; i2 = e;
            }
        }
    }

    float e2 = expf(m2 - m1);
    float denom = 1.f + e2;
    out[t * 2 + 0] = 1.f / denom;
    out[t * 2 + 1] = e2 / denom;
    out[NTOK * 2 + t * 2 + 0] = (float)i1;
    out[NTOK * 2 + t * 2 + 1] = (float)i2;
}

template <int NS>
static void launch_ns(const float* x, const float* gw, float* ws, float* out,
                      hipStream_t stream) {
    moe_partial_kernel<NS>
        <<<dim3((NTOK / 256) * NS), dim3(256), 0, stream>>>(x, gw, ws);
    moe_reduce_kernel<NS>
        <<<dim3(NTOK / 128), dim3(128), 0, stream>>>(ws, out);
}

extern "C" void kernel_launch(void* const* d_in, const int* in_sizes, int n_in,
                              void* d_out, int out_size, void* d_ws, size_t ws_size,
                              hipStream_t stream) {
    const float* x  = (const float*)d_in[0];   // [4,4096,2048] f32
    const float* gw = (const float*)d_in[1];   // [64,2048] f32
    float* out = (float*)d_out;
    float* ws  = (float*)d_ws;

    const size_t per_slice = (size_t)SLICE_ELTS * sizeof(float);  // 4 MiB
    if      (ws_size >= 8 * per_slice) launch_ns<8>(x, gw, ws, out, stream);
    else if (ws_size >= 4 * per_slice) launch_ns<4>(x, gw, ws, out, stream);
    else if (ws_size >= 2 * per_slice) launch_ns<2>(x, gw, ws, out, stream);
    else                               launch_ns<1>(x, gw, ws, out, stream);
}

// Round 7
// 99.325 us; speedup vs baseline: 2.1164x; 1.4277x over previous
//
#include <hip/hip_runtime.h>
#include <math.h>

// MoE router: logits[16384,64] = X[16384,2048] @ W^T (fp32), top-2, softmax(2).
// Outputs flat: weights [16384*2] f32, then indices [16384*2] as float.
//
// R1: runtime-indexed acc -> scratch spill.
// R3: register-staged LDS tiles -> spill (2.7GB traffic).
// R4: W-in-LDS only: 167us, FETCH 488MB (4-wave X duplication thru L2).
// R5: W scalar loads: FETCH compulsory but dependent s_load chains, 277us.
// R6: DC=32 + X ping-pong: 141us, FETCH 234MB, VALU 30%. Root cause left:
//     X loads are row-per-lane gathers (8KB lane stride) -> 64 L1 line
//     transactions per load instr; TA-pipe bound.
// R7: X ALSO staged to LDS via global_load_lds (coalesced, 0 registers),
//     XOR-swizzled via pre-swizzled GLOBAL source (m173): LDS dest linear,
//     source col c = c' ^ (tok&7). Compute reads X per-lane ds_read_b128 at
//     8-way conflict (~2.9x, budgeted), W wave-uniform broadcast. LDS 80KB.

#define NTOK 16384
#define DDIM 2048
#define NEXP 64
#define DC 32                      // d per LDS chunk
#define SLICE_ELTS (NTOK * NEXP)   // floats per ws slice

__device__ static inline void gload_lds16(const float* gsrc, float* ldst) {
    __builtin_amdgcn_global_load_lds(
        (const __attribute__((address_space(1))) void*)gsrc,
        (__attribute__((address_space(3))) void*)ldst, 16, 0, 0);
}

template <int NS>
__global__ __launch_bounds__(256, 2) void moe_partial_kernel(
    const float* __restrict__ x,      // [NTOK, DDIM]
    const float* __restrict__ gw,     // [NEXP, DDIM]
    float* __restrict__ ws)           // [NS][NTOK][NEXP]
{
    // X chunk: [256 tok][8 c16] float4, swizzled c' = c ^ (tok&7). 32KB x2.
    // W chunk: [64 e][8 c16] float4, linear.                        8KB x2.
    __shared__ float4 Xl[2][256 * 8];
    __shared__ float4 Wl[2][NEXP * 8];

    const int tid  = threadIdx.x;
    const int lane = tid & 63;
    const int eg   = __builtin_amdgcn_readfirstlane(tid >> 6); // 0..3
    const int dsl  = blockIdx.x & (NS - 1);
    const int tg   = blockIdx.x / NS;
    const int T0   = tg * 256;
    const int DSL  = DDIM / NS;          // 256 for NS=8
    const int NCH  = DSL / DC;           // 8
    const int d0   = dsl * DSL;

    // ---- staging: X 2048 units (8/thread), W 512 units (2/thread).
    // X unit u: tok = u>>3, c' = u&7, SOURCE col c = c' ^ (tok&7)  (m173:
    // linear LDS dest + pre-swizzled global source). Consecutive u cover a
    // contiguous (permuted) 128B row window -> coalesced.
#define STAGE(ch, buf)                                                        \
    {                                                                         \
        const int dcol = d0 + (ch) * DC;                                      \
        _Pragma("unroll")                                                     \
        for (int s = 0; s < 8; ++s) {                                         \
            const int u   = tid + s * 256;                                    \
            const int tok = u >> 3;                                           \
            const int c   = (u & 7) ^ (tok & 7);                              \
            gload_lds16(x + (size_t)(T0 + tok) * DDIM + dcol + c * 4,         \
                        (float*)&Xl[buf][u]);                                 \
        }                                                                     \
        _Pragma("unroll")                                                     \
        for (int s = 0; s < 2; ++s) {                                         \
            const int u = tid + s * 256;                                      \
            gload_lds16(gw + (size_t)(u >> 3) * DDIM + dcol + (u & 7) * 4,    \
                        (float*)&Wl[buf][u]);                                 \
        }                                                                     \
    }

    float acc[4][16];
#pragma unroll
    for (int t = 0; t < 4; ++t)
#pragma unroll
        for (int e = 0; e < 16; ++e) acc[t][e] = 0.f;

    STAGE(0, 0);
    __syncthreads();

    int cur = 0;
    for (int ch = 0; ch < NCH; ++ch) {
        if (ch + 1 < NCH) STAGE(ch + 1, cur ^ 1);   // async DMA, no registers

        const float4* Xc = Xl[cur];
        const float4* Wc = &Wl[cur][eg * 16 * 8];   // this wave's 16 experts
        const int     kx = lane & 7;                // X swizzle key

#pragma unroll 2
        for (int d4 = 0; d4 < DC / 4; ++d4) {
            float4 xv[4];
#pragma unroll
            for (int t = 0; t < 4; ++t)             // tok = lane + 64t
                xv[t] = Xc[(lane + 64 * t) * 8 + (d4 ^ kx)];
#pragma unroll
            for (int e = 0; e < 16; ++e) {
                float4 wv = Wc[e * 8 + d4];         // uniform -> broadcast
#pragma unroll
                for (int t = 0; t < 4; ++t) {
                    acc[t][e] = fmaf(xv[t].x, wv.x, acc[t][e]);
                    acc[t][e] = fmaf(xv[t].y, wv.y, acc[t][e]);
                    acc[t][e] = fmaf(xv[t].z, wv.z, acc[t][e]);
                    acc[t][e] = fmaf(xv[t].w, wv.w, acc[t][e]);
                }
            }
        }
        __syncthreads();
        cur ^= 1;
    }
#undef STAGE

    // partials: ws[dsl][tok][exp], 64B contiguous per lane per token group
    float* wsl = ws + (size_t)dsl * SLICE_ELTS;
#pragma unroll
    for (int t = 0; t < 4; ++t) {
        float* row = wsl + (size_t)(T0 + lane + 64 * t) * NEXP + eg * 16;
#pragma unroll
        for (int q = 0; q < 4; ++q) {
            float4 v = make_float4(acc[t][q * 4 + 0], acc[t][q * 4 + 1],
                                   acc[t][q * 4 + 2], acc[t][q * 4 + 3]);
            *reinterpret_cast<float4*>(row + q * 4) = v;
        }
    }
}

template <int NS>
__global__ __launch_bounds__(128) void moe_reduce_kernel(
    const float* __restrict__ ws,     // [NS][NTOK][NEXP]
    float* __restrict__ out)          // weights then indices
{
    const int t = blockIdx.x * 128 + threadIdx.x;   // token
    float m1 = -INFINITY, m2 = -INFINITY;
    int i1 = 0, i2 = 0;

    const float* base = ws + (size_t)t * NEXP;
    for (int e4 = 0; e4 < 16; ++e4) {
        float4 s = *reinterpret_cast<const float4*>(base + e4 * 4);
#pragma unroll
        for (int sl = 1; sl < NS; ++sl) {           // ascending-D order
            float4 p = *reinterpret_cast<const float4*>(
                base + (size_t)sl * SLICE_ELTS + e4 * 4);
            s.x += p.x; s.y += p.y; s.z += p.z; s.w += p.w;
        }
        float v[4] = {s.x, s.y, s.z, s.w};
#pragma unroll
        for (int q = 0; q < 4; ++q) {
            const int e = e4 * 4 + q;
            if (v[q] > m1) {            // strict '>' = lowest index on ties
                m2 = m1; i2 = i1;
                m1 = v[q]; i1 = e;
            } else if (v[q] > m2) {
                m2 = v[q]; i2 = e;
            }
        }
    }

    float e2 = expf(m2 - m1);
    float denom = 1.f + e2;
    out[t * 2 + 0] = 1.f / denom;
    out[t * 2 + 1] = e2 / denom;
    out[NTOK * 2 + t * 2 + 0] = (float)i1;
    out[NTOK * 2 + t * 2 + 1] = (float)i2;
}

template <int NS>
static void launch_ns(const float* x, const float* gw, float* ws, float* out,
                      hipStream_t stream) {
    moe_partial_kernel<NS>
        <<<dim3((NTOK / 256) * NS), dim3(256), 0, stream>>>(x, gw, ws);
    moe_reduce_kernel<NS>
        <<<dim3(NTOK / 128), dim3(128), 0, stream>>>(ws, out);
}

extern "C" void kernel_launch(void* const* d_in, const int* in_sizes, int n_in,
                              void* d_out, int out_size, void* d_ws, size_t ws_size,
                              hipStream_t stream) {
    const float* x  = (const float*)d_in[0];   // [4,4096,2048] f32
    const float* gw = (const float*)d_in[1];   // [64,2048] f32
    float* out = (float*)d_out;
    float* ws  = (float*)d_ws;

    const size_t per_slice = (size_t)SLICE_ELTS * sizeof(float);  // 4 MiB
    if      (ws_size >= 8 * per_slice) launch_ns<8>(x, gw, ws, out, stream);
    else if (ws_size >= 4 * per_slice) launch_ns<4>(x, gw, ws, out, stream);
    else if (ws_size >= 2 * per_slice) launch_ns<2>(x, gw, ws, out, stream);
    else                               launch_ns<1>(x, gw, ws, out, stream);
}

// Round 9
// 70.450 us; speedup vs baseline: 2.9838x; 1.4099x over previous
//
#include <hip/hip_runtime.h>
#include <math.h>

// MoE router: logits[16384,64] = X[16384,2048] @ W^T, top-2, softmax(2).
// Outputs flat: weights [16384*2] f32, then indices [16384*2] as float.
//
// R7 (fp32 VALU): 99us, structurally LDS<->VALU balanced at 43% VALU.
// R8 (bf16 MFMA, 2-split/3-product): weights PASSED (layout verified) but
//     indices flipped on near-ties -- logit err ~1.5e-5 too coarse.
// R9: bf16x6. Exact truncating 3-way split (mask -> subtract is exact):
//     x = xh+xm+xl (+r, |r|<=2^-24|x|), same for w. Products hh,hm,mh,
//     hl,mm,lh (dropped ml,lm,ll ~2^-24) -> logit err ~1.5e-6, same class
//     as the passing fp32 kernels. MFMA ~12us, LDS ~13us, HBM X read ~21us
//     -> still HBM-bound.

#define NTOK 16384
#define DDIM 2048
#define NEXP 64
#define MBLK 64
#define KC   32
#define NS   4
#define SLICE_ELTS (NTOK * NEXP)

typedef __attribute__((ext_vector_type(8))) short bf16x8;
typedef __attribute__((ext_vector_type(4))) float f32x4;

__device__ static inline void gload_lds16(const void* gsrc, void* ldst) {
    __builtin_amdgcn_global_load_lds(
        (const __attribute__((address_space(1))) void*)gsrc,
        (__attribute__((address_space(3))) void*)ldst, 16, 0, 0);
}

// exact 3-way truncating split: x = h + m + l + r, |r| <= 2^-24 |x|
__device__ static inline void split3(float x, short& h, short& m, short& l) {
    unsigned uh = __float_as_uint(x);
    h = (short)(uh >> 16);
    float r1 = x - __uint_as_float(uh & 0xffff0000u);   // exact
    unsigned um = __float_as_uint(r1);
    m = (short)(um >> 16);
    float r2 = r1 - __uint_as_float(um & 0xffff0000u);  // exact
    l = (short)(__float_as_uint(r2) >> 16);
}

// ---- prep: split W into bf16 h/m/l (deterministic, every launch) ----
__global__ __launch_bounds__(256) void wsplit_kernel(
    const float* __restrict__ gw, short* __restrict__ wh,
    short* __restrict__ wm, short* __restrict__ wl)
{
    for (int i = blockIdx.x * 256 + threadIdx.x; i < NEXP * DDIM;
         i += gridDim.x * 256) {
        short h, m, l;
        split3(gw[i], h, m, l);
        wh[i] = h; wm[i] = m; wl[i] = l;
    }
}

// ---- main: partial logits via MFMA bf16x6, split-K ----
__global__ __launch_bounds__(256) void moe_mfma_kernel(
    const float* __restrict__ x,      // [NTOK, DDIM] f32
    const short* __restrict__ wh,     // [NEXP, DDIM] bf16 bits
    const short* __restrict__ wm,
    const short* __restrict__ wl,
    float* __restrict__ part)         // [NS][NTOK][NEXP]
{
    // 16B units: row r (0..63), k-unit c (0..3), phys col = c ^ (r&3).
    __shared__ bf16x8 XH[2][MBLK * 4], XM[2][MBLK * 4], XL[2][MBLK * 4];
    __shared__ bf16x8 WH[2][NEXP * 4], WM[2][NEXP * 4], WL[2][NEXP * 4];

    const int tid  = threadIdx.x;
    const int lane = tid & 63;
    const int w    = tid >> 6;            // wave 0..3 -> token sub-tile
    const int dsl  = blockIdx.x & (NS - 1);
    const int tg   = blockIdx.x / NS;
    const int T0   = tg * MBLK;
    const int KSL  = DDIM / NS;           // 512
    const int NCH  = KSL / KC;            // 16
    const int k0s  = dsl * KSL;

    // staging map: thread tid -> row sr, k-unit sc
    const int sr = tid >> 2;              // 0..63
    const int sc = tid & 3;               // 0..3
    const int sdst = sr * 4 + (sc ^ (sr & 3));   // X LDS dest (manual write)
    const int wsk  = (sc ^ (sr & 3)) * 8;        // W source k-offset (shorts)
                                                 // (gload dest = tid, linear)
    // fragment read map: lane l -> row fr, k-group fg
    const int fr = lane & 15;
    const int fg = lane >> 4;
    const int fsw = fg ^ (fr & 3);
    const int aidx = (w * 16 + fr) * 4 + fsw;

    f32x4 acc[4] = {{0.f,0.f,0.f,0.f},{0.f,0.f,0.f,0.f},
                    {0.f,0.f,0.f,0.f},{0.f,0.f,0.f,0.f}};
    float4 xa, xb;

#define XLOAD(ch)                                                             \
    {                                                                         \
        const float* p = x + (size_t)(T0 + sr) * DDIM + k0s + (ch) * KC + sc * 8; \
        xa = *reinterpret_cast<const float4*>(p);                             \
        xb = *reinterpret_cast<const float4*>(p + 4);                         \
    }
#define WSTAGE(ch, buf)                                                       \
    {                                                                         \
        const size_t off = (size_t)sr * DDIM + k0s + (ch) * KC + wsk;         \
        gload_lds16(wh + off, &WH[buf][tid]);                                 \
        gload_lds16(wm + off, &WM[buf][tid]);                                 \
        gload_lds16(wl + off, &WL[buf][tid]);                                 \
    }
#define XWRITE(buf)                                                           \
    {                                                                         \
        bf16x8 h8, m8, l8;                                                    \
        float xf[8] = {xa.x, xa.y, xa.z, xa.w, xb.x, xb.y, xb.z, xb.w};       \
        _Pragma("unroll")                                                     \
        for (int j = 0; j < 8; ++j) {                                         \
            short hj, mj, lj;                                                 \
            split3(xf[j], hj, mj, lj);                                        \
            h8[j] = hj; m8[j] = mj; l8[j] = lj;                               \
        }                                                                     \
        XH[buf][sdst] = h8;                                                   \
        XM[buf][sdst] = m8;                                                   \
        XL[buf][sdst] = l8;                                                   \
    }

    XLOAD(0); WSTAGE(0, 0); XWRITE(0);
    __syncthreads();

    int cur = 0;
    for (int ch = 0; ch < NCH; ++ch) {
        const bool pf = (ch + 1 < NCH);
        if (pf) { XLOAD(ch + 1); WSTAGE(ch + 1, cur ^ 1); }  // issue early

        const bf16x8 ah = XH[cur][aidx];
        const bf16x8 am = XM[cur][aidx];
        const bf16x8 al = XL[cur][aidx];
#pragma unroll
        for (int n = 0; n < 4; ++n) {
            const int bidx = (n * 16 + fr) * 4 + fsw;
            const bf16x8 bh = WH[cur][bidx];
            const bf16x8 bm = WM[cur][bidx];
            const bf16x8 bl = WL[cur][bidx];
            // small products first (rounding), then the big one
            acc[n] = __builtin_amdgcn_mfma_f32_16x16x32_bf16(al, bh, acc[n], 0, 0, 0);
            acc[n] = __builtin_amdgcn_mfma_f32_16x16x32_bf16(am, bm, acc[n], 0, 0, 0);
            acc[n] = __builtin_amdgcn_mfma_f32_16x16x32_bf16(ah, bl, acc[n], 0, 0, 0);
            acc[n] = __builtin_amdgcn_mfma_f32_16x16x32_bf16(am, bh, acc[n], 0, 0, 0);
            acc[n] = __builtin_amdgcn_mfma_f32_16x16x32_bf16(ah, bm, acc[n], 0, 0, 0);
            acc[n] = __builtin_amdgcn_mfma_f32_16x16x32_bf16(ah, bh, acc[n], 0, 0, 0);
        }

        if (pf) XWRITE(cur ^ 1);          // vmcnt wait lands here, post-MFMA
        __syncthreads();
        cur ^= 1;
    }
#undef XLOAD
#undef WSTAGE
#undef XWRITE

    // C/D: col = fr (expert in n-tile), row = fg*4 + j (token in w-tile) [m89]
    float* wsl = part + (size_t)dsl * SLICE_ELTS;
#pragma unroll
    for (int n = 0; n < 4; ++n)
#pragma unroll
        for (int j = 0; j < 4; ++j) {
            const int tok = T0 + w * 16 + fg * 4 + j;
            wsl[(size_t)tok * NEXP + n * 16 + fr] = acc[n][j];
        }
}

// ---- reduce: sum slices (ascending), top-2, softmax ----
__global__ __launch_bounds__(128) void moe_reduce_kernel(
    const float* __restrict__ part,   // [NS][NTOK][NEXP]
    float* __restrict__ out)
{
    const int t = blockIdx.x * 128 + threadIdx.x;
    float m1 = -INFINITY, m2 = -INFINITY;
    int i1 = 0, i2 = 0;

    const float* base = part + (size_t)t * NEXP;
    for (int e4 = 0; e4 < 16; ++e4) {
        float4 s = *reinterpret_cast<const float4*>(base + e4 * 4);
#pragma unroll
        for (int sl = 1; sl < NS; ++sl) {
            float4 p = *reinterpret_cast<const float4*>(
                base + (size_t)sl * SLICE_ELTS + e4 * 4);
            s.x += p.x; s.y += p.y; s.z += p.z; s.w += p.w;
        }
        float v[4] = {s.x, s.y, s.z, s.w};
#pragma unroll
        for (int q = 0; q < 4; ++q) {
            const int e = e4 * 4 + q;
            if (v[q] > m1) {              // strict '>' = lowest index on ties
                m2 = m1; i2 = i1;
                m1 = v[q]; i1 = e;
            } else if (v[q] > m2) {
                m2 = v[q]; i2 = e;
            }
        }
    }

    float e2 = expf(m2 - m1);
    float denom = 1.f + e2;
    out[t * 2 + 0] = 1.f / denom;
    out[t * 2 + 1] = e2 / denom;
    out[NTOK * 2 + t * 2 + 0] = (float)i1;
    out[NTOK * 2 + t * 2 + 1] = (float)i2;
}

extern "C" void kernel_launch(void* const* d_in, const int* in_sizes, int n_in,
                              void* d_out, int out_size, void* d_ws, size_t ws_size,
                              hipStream_t stream) {
    const float* x  = (const float*)d_in[0];   // [4,4096,2048] f32
    const float* gw = (const float*)d_in[1];   // [64,2048] f32
    float* out = (float*)d_out;

    // ws layout: Wh|Wm|Wl (3 x 256KB bf16) | partials NS x 4MiB  (~16.8 MB;
    // ws >= 32MB proven in R4's NS=8 config)
    short* wh = (short*)d_ws;
    short* wm = wh + NEXP * DDIM;
    short* wl = wm + NEXP * DDIM;
    float* part = (float*)((char*)d_ws + 3 * (size_t)NEXP * DDIM * sizeof(short));

    wsplit_kernel<<<dim3(128), dim3(256), 0, stream>>>(gw, wh, wm, wl);
    moe_mfma_kernel<<<dim3((NTOK / MBLK) * NS), dim3(256), 0, stream>>>(
        x, wh, wm, wl, part);
    moe_reduce_kernel<<<dim3(NTOK / 128), dim3(128), 0, stream>>>(part, out);
}

// Round 10
// 55.247 us; speedup vs baseline: 3.8049x; 1.2752x over previous
//
#include <hip/hip_runtime.h>
#include <math.h>

// MoE router: logits[16384,64] = X[16384,2048] @ W^T, top-2, softmax(2).
// Outputs flat: weights [16384*2] f32, then indices [16384*2] as float.
//
// R7 (fp32 VALU): 99us, LDS<->VALU balanced at 43% VALU.
// R8 (bf16 MFMA 2-split): weights passed (layout verified), indices flipped
//     -- logit err 1.5e-5 too coarse.
// R9 (bf16x6, X split in XWRITE): 70us, PASS. But MfmaUtil 12 / VALU 12 /
//     occupancy 22% -> latency-bound: XLOAD->split3->XWRITE->vmcnt(0) chain
//     serializes per chunk at only 3 blocks/CU.
// R10: X staged as RAW F32 via global_load_lds (all staging = DMA, zero
//     registers); split3 moved to registers after the fragment read.
//     LDS 40KB -> 4 blocks/CU (16 waves). X frags: 8-unit XOR swizzle,
//     per-logical-unit XOR keeps k-order; 2-way conflicts (free). W: proven
//     4-unit swizzle. A/B use identical k-mapping (verified R8/R9).

#define NTOK 16384
#define DDIM 2048
#define NEXP 64
#define MBLK 64
#define KC   32
#define NS   4
#define SLICE_ELTS (NTOK * NEXP)

typedef __attribute__((ext_vector_type(8))) short bf16x8;
typedef __attribute__((ext_vector_type(4))) float f32x4;

__device__ static inline void gload_lds16(const void* gsrc, void* ldst) {
    __builtin_amdgcn_global_load_lds(
        (const __attribute__((address_space(1))) void*)gsrc,
        (__attribute__((address_space(3))) void*)ldst, 16, 0, 0);
}

// exact 3-way truncating split: x = h + m + l + r, |r| <= 2^-24 |x|
__device__ static inline void split3(float x, short& h, short& m, short& l) {
    unsigned uh = __float_as_uint(x);
    h = (short)(uh >> 16);
    float r1 = x - __uint_as_float(uh & 0xffff0000u);   // exact
    unsigned um = __float_as_uint(r1);
    m = (short)(um >> 16);
    float r2 = r1 - __uint_as_float(um & 0xffff0000u);  // exact
    l = (short)(__float_as_uint(r2) >> 16);
}

// ---- prep: split W into bf16 h/m/l (deterministic, every launch) ----
__global__ __launch_bounds__(256) void wsplit_kernel(
    const float* __restrict__ gw, short* __restrict__ wh,
    short* __restrict__ wm, short* __restrict__ wl)
{
    for (int i = blockIdx.x * 256 + threadIdx.x; i < NEXP * DDIM;
         i += gridDim.x * 256) {
        short h, m, l;
        split3(gw[i], h, m, l);
        wh[i] = h; wm[i] = m; wl[i] = l;
    }
}

// ---- main: partial logits via MFMA bf16x6, split-K ----
__global__ __launch_bounds__(256, 4) void moe_mfma_kernel(
    const float* __restrict__ x,      // [NTOK, DDIM] f32
    const short* __restrict__ wh,     // [NEXP, DDIM] bf16 bits
    const short* __restrict__ wm,
    const short* __restrict__ wl,
    float* __restrict__ part)         // [NS][NTOK][NEXP]
{
    // X tile: [64 tok][8 units of 4 f32], phys unit = c' (contains source
    //         col c'^ (tok&7)).  2 x 8KB.
    // W tile: [64 e][4 units of bf16x8], phys = c ^ (e&3).  3 x 2 x 4KB.
    __shared__ float4 XF[2][MBLK * 8];
    __shared__ bf16x8 WH[2][NEXP * 4], WM[2][NEXP * 4], WL[2][NEXP * 4];

    const int tid  = threadIdx.x;
    const int lane = tid & 63;
    const int w    = tid >> 6;            // wave 0..3 -> token sub-tile
    const int dsl  = blockIdx.x & (NS - 1);
    const int tg   = blockIdx.x / NS;
    const int T0   = tg * MBLK;
    const int KSL  = DDIM / NS;           // 512
    const int NCH  = KSL / KC;            // 16
    const int k0s  = dsl * KSL;

    // W staging map: thread tid -> e = tid>>2, unit sc = tid&3
    const int we  = tid >> 2;
    const int wsk = ((tid & 3) ^ (we & 3)) * 8;  // source k-offset (shorts)

    // fragment read map: lane l -> row fr, k-group fg
    const int fr  = lane & 15;
    const int fg  = lane >> 4;
    const int fsw = fg ^ (fr & 3);               // W phys unit key
    const int arow = (w * 16 + fr) * 8;          // X row base (units)
    const int akey = fr & 7;                     // X swizzle key (row&7)

    f32x4 acc[4] = {{0.f,0.f,0.f,0.f},{0.f,0.f,0.f,0.f},
                    {0.f,0.f,0.f,0.f},{0.f,0.f,0.f,0.f}};

    // staging: X 512 units (2/thread), W 3 x 256 units (1/thread each)
#define STAGE(ch, buf)                                                        \
    {                                                                         \
        const int kk = k0s + (ch) * KC;                                       \
        _Pragma("unroll")                                                     \
        for (int s = 0; s < 2; ++s) {                                         \
            const int u   = tid + s * 256;                                    \
            const int tok = u >> 3;                                           \
            const int c   = (u & 7) ^ (tok & 7);                              \
            gload_lds16(x + (size_t)(T0 + tok) * DDIM + kk + c * 4,           \
                        &XF[buf][u]);                                         \
        }                                                                     \
        const size_t woff = (size_t)we * DDIM + kk + wsk;                     \
        gload_lds16(wh + woff, &WH[buf][tid]);                                \
        gload_lds16(wm + woff, &WM[buf][tid]);                                \
        gload_lds16(wl + woff, &WL[buf][tid]);                                \
    }

    STAGE(0, 0);
    __syncthreads();

    int cur = 0;
    for (int ch = 0; ch < NCH; ++ch) {
        if (ch + 1 < NCH) STAGE(ch + 1, cur ^ 1);   // async DMA, no registers

        // A fragment: read 2 f32x4 units (per-logical-unit XOR -> k-order
        // preserved), split3 in registers.
        float4 a0 = XF[cur][arow + ((fg * 2 + 0) ^ akey)];
        float4 a1 = XF[cur][arow + ((fg * 2 + 1) ^ akey)];
        bf16x8 ah, am, al;
        {
            float xf8[8] = {a0.x, a0.y, a0.z, a0.w, a1.x, a1.y, a1.z, a1.w};
#pragma unroll
            for (int j = 0; j < 8; ++j) {
                short hj, mj, lj;
                split3(xf8[j], hj, mj, lj);
                ah[j] = hj; am[j] = mj; al[j] = lj;
            }
        }

#pragma unroll
        for (int n = 0; n < 4; ++n) {
            const int bidx = (n * 16 + fr) * 4 + fsw;
            const bf16x8 bh = WH[cur][bidx];
            const bf16x8 bm = WM[cur][bidx];
            const bf16x8 bl = WL[cur][bidx];
            // small products first (rounding), then the big one
            acc[n] = __builtin_amdgcn_mfma_f32_16x16x32_bf16(al, bh, acc[n], 0, 0, 0);
            acc[n] = __builtin_amdgcn_mfma_f32_16x16x32_bf16(am, bm, acc[n], 0, 0, 0);
            acc[n] = __builtin_amdgcn_mfma_f32_16x16x32_bf16(ah, bl, acc[n], 0, 0, 0);
            acc[n] = __builtin_amdgcn_mfma_f32_16x16x32_bf16(am, bh, acc[n], 0, 0, 0);
            acc[n] = __builtin_amdgcn_mfma_f32_16x16x32_bf16(ah, bm, acc[n], 0, 0, 0);
            acc[n] = __builtin_amdgcn_mfma_f32_16x16x32_bf16(ah, bh, acc[n], 0, 0, 0);
        }

        __syncthreads();
        cur ^= 1;
    }
#undef STAGE

    // C/D: col = fr (expert in n-tile), row = fg*4 + j (token in w-tile) [m89]
    float* wsl = part + (size_t)dsl * SLICE_ELTS;
#pragma unroll
    for (int n = 0; n < 4; ++n)
#pragma unroll
        for (int j = 0; j < 4; ++j) {
            const int tok = T0 + w * 16 + fg * 4 + j;
            wsl[(size_t)tok * NEXP + n * 16 + fr] = acc[n][j];
        }
}

// ---- reduce: sum slices (ascending), top-2, softmax ----
__global__ __launch_bounds__(128) void moe_reduce_kernel(
    const float* __restrict__ part,   // [NS][NTOK][NEXP]
    float* __restrict__ out)
{
    const int t = blockIdx.x * 128 + threadIdx.x;
    float m1 = -INFINITY, m2 = -INFINITY;
    int i1 = 0, i2 = 0;

    const float* base = part + (size_t)t * NEXP;
    for (int e4 = 0; e4 < 16; ++e4) {
        float4 s = *reinterpret_cast<const float4*>(base + e4 * 4);
#pragma unroll
        for (int sl = 1; sl < NS; ++sl) {
            float4 p = *reinterpret_cast<const float4*>(
                base + (size_t)sl * SLICE_ELTS + e4 * 4);
            s.x += p.x; s.y += p.y; s.z += p.z; s.w += p.w;
        }
        float v[4] = {s.x, s.y, s.z, s.w};
#pragma unroll
        for (int q = 0; q < 4; ++q) {
            const int e = e4 * 4 + q;
            if (v[q] > m1) {              // strict '>' = lowest index on ties
                m2 = m1; i2 = i1;
                m1 = v[q]; i1 = e;
            } else if (v[q] > m2) {
                m2 = v[q]; i2 = e;
            }
        }
    }

    float e2 = expf(m2 - m1);
    float denom = 1.f + e2;
    out[t * 2 + 0] = 1.f / denom;
    out[t * 2 + 1] = e2 / denom;
    out[NTOK * 2 + t * 2 + 0] = (float)i1;
    out[NTOK * 2 + t * 2 + 1] = (float)i2;
}

extern "C" void kernel_launch(void* const* d_in, const int* in_sizes, int n_in,
                              void* d_out, int out_size, void* d_ws, size_t ws_size,
                              hipStream_t stream) {
    const float* x  = (const float*)d_in[0];   // [4,4096,2048] f32
    const float* gw = (const float*)d_in[1];   // [64,2048] f32
    float* out = (float*)d_out;

    // ws layout: Wh|Wm|Wl (3 x 256KB bf16) | partials NS x 4MiB (~17 MB)
    short* wh = (short*)d_ws;
    short* wm = wh + NEXP * DDIM;
    short* wl = wm + NEXP * DDIM;
    float* part = (float*)((char*)d_ws + 3 * (size_t)NEXP * DDIM * sizeof(short));

    wsplit_kernel<<<dim3(128), dim3(256), 0, stream>>>(gw, wh, wm, wl);
    moe_mfma_kernel<<<dim3((NTOK / MBLK) * NS), dim3(256), 0, stream>>>(
        x, wh, wm, wl, part);
    moe_reduce_kernel<<<dim3(NTOK / 128), dim3(128), 0, stream>>>(part, out);
}